// Round 7
// baseline (143.198 us; speedup 1.0000x reference)
//
#include <hip/hip_runtime.h>
#include <cstddef>

#define BN_EPS 1e-5f
#define VST 68   // LDS row stride (floats): 272B = 17*16B -> 16B-aligned rows

__device__ __forceinline__ float sigmoidf_(float x) {
    return __builtin_amdgcn_rcpf(1.0f + __expf(-x));
}

// Hierarchical grid barrier: 1024 blocks, 16 groups of 64.
// Counters zeroed by hipMemsetAsync before every launch (graph-captured).
// Layout per phase: 272 ints (16 group counters spaced 16 ints + root at 256).
__device__ __forceinline__ void gridbar(int* C, int phase) {
    __syncthreads();
    if (threadIdx.x == 0) {
        int grp = blockIdx.x >> 6;                 // 0..15
        int* gc = C + phase * 272 + grp * 16;
        int* rc = C + phase * 272 + 256;
        __threadfence();                           // agent-scope release
        int old = __hip_atomic_fetch_add(gc, 1, __ATOMIC_ACQ_REL,
                                         __HIP_MEMORY_SCOPE_AGENT);
        if (old == 63)
            __hip_atomic_fetch_add(rc, 1, __ATOMIC_ACQ_REL,
                                   __HIP_MEMORY_SCOPE_AGENT);
        while (__hip_atomic_load(rc, __ATOMIC_ACQUIRE,
                                 __HIP_MEMORY_SCOPE_AGENT) < 16)
            __builtin_amdgcn_s_sleep(2);
    }
    __syncthreads();
}

// One kernel, 1024 blocks (one per (b,c) plane), 256 threads.
// Phase 0: plane->LDS + pool->ws + lin(slin, LDS-local)
// gridbar; Phase 1: fc1: wave w computes dp[b=w][j=blockIdx]
// gridbar; Phase 2: fc2 gates for own bc; Phase 3: stencil; Phase 4: q proj.
__global__ __launch_bounds__(256, 4) void fused_kernel(
    const float* __restrict__ value, const float* __restrict__ query,
    const float* __restrict__ W1, const float* __restrict__ b1,
    const float* __restrict__ gamma, const float* __restrict__ beta,
    const float* __restrict__ mean, const float* __restrict__ var,
    const float* __restrict__ W2, const float* __restrict__ b2,
    const float* __restrict__ Wl, const float* __restrict__ bl,
    const float* __restrict__ Wd, const float* __restrict__ bd,
    int* __restrict__ cnt, float* __restrict__ pooled, float* __restrict__ dp,
    float* __restrict__ q_out, float* __restrict__ y_out) {

    __shared__ __align__(16) float vpad[66 * VST];
    __shared__ __align__(16) float ppad[66 * VST];
    __shared__ float linpart[180];
    __shared__ float slin[18];
    __shared__ float scat[18];
    __shared__ float gAB[2];
    __shared__ float ws4[4];

    const int t  = threadIdx.x;
    const int bc = blockIdx.x;            // 0..1023
    const int b  = bc >> 8, c = bc & 255;
    const int w  = t >> 6, lane = t & 63;

    // ---- Phase 0: halo zero + plane load (stays in LDS!) + pool + lin ----
    for (int i = t; i < 260; i += 256) {
        int row, col;
        if (i < 132) { row = (i & 1) ? 65 : 0; col = 2 + (i >> 1); }
        else { int u = i - 132; row = 1 + (u & 63); col = (u & 64) ? 67 : 2; }
        vpad[row * VST + col] = 0.f;
        ppad[row * VST + col] = 0.f;
    }
    const float* vp = value + (size_t)bc * 4096;
    float ps = 0.f;
    #pragma unroll
    for (int i = 0; i < 16; ++i) {
        int idx = (i << 8) + t;
        float v = vp[idx];
        ps += v;
        vpad[((idx >> 6) + 1) * VST + 3 + (idx & 63)] = v;
    }
    #pragma unroll
    for (int off = 32; off > 0; off >>= 1) ps += __shfl_down(ps, off);
    if (lane == 0) ws4[w] = ps;

    if (t < 180) {                        // lin partials: k = t/10, part = t%10
        int k = t / 10, p = t - k * 10;
        float s = 0.f;
        const float* wlr = Wl + k * 100 + p * 10;
        const float* qr  = query + (size_t)(p * 10) * 1024 + bc;
        #pragma unroll
        for (int i = 0; i < 10; ++i) s = fmaf(qr[(size_t)i * 1024], wlr[i], s);
        linpart[t] = s;
    }
    __syncthreads();
    if (t == 0) pooled[bc] = (ws4[0] + ws4[1] + ws4[2] + ws4[3]) * (1.0f / 4096.0f);
    if (t < 18) {
        float s = bl[t];
        #pragma unroll
        for (int p = 0; p < 10; ++p) s += linpart[t * 10 + p];
        slin[t] = s;
    }
    gridbar(cnt, 0);

    // ---- Phase 1: fc1: dp[b=w][j=bc], one wave per b ----
    {
        const float4* pr = (const float4*)(pooled + w * 256);
        const float4* wr = (const float4*)(W1 + (size_t)bc * 256);
        float4 p = pr[lane], ww = wr[lane];
        float s = p.x * ww.x + p.y * ww.y + p.z * ww.z + p.w * ww.w;
        #pragma unroll
        for (int off = 32; off > 0; off >>= 1) s += __shfl_down(s, off);
        if (lane == 0) {
            s += b1[bc];
            s = (s - mean[bc]) * rsqrtf(var[bc] + BN_EPS) * gamma[bc] + beta[bc];
            dp[w * 1024 + bc] = fmaxf(s, 0.f);
        }
    }
    gridbar(cnt, 1);

    // ---- Phase 2: fc2 gates for own bc (waves 0,1) ----
    if (w < 2) {
        const float4* dpr  = (const float4*)(dp + b * 1024);
        const float4* wrow = (const float4*)(W2 + (size_t)(c + w * 256) * 1024);
        float s = 0.f;
        #pragma unroll
        for (int j = 0; j < 4; ++j) {
            float4 d = dpr[lane + 64 * j], ww = wrow[lane + 64 * j];
            s += d.x * ww.x + d.y * ww.y + d.z * ww.z + d.w * ww.w;
        }
        #pragma unroll
        for (int off = 32; off > 0; off >>= 1) s += __shfl_xor(s, off);
        if (lane == 0) gAB[w] = sigmoidf_(s + b2[c + w * 256]);
    }
    __syncthreads();
    if (t < 18) scat[t] = slin[t] * (t < 9 ? gAB[0] : gAB[1]);
    __syncthreads();

    float f[9], wkk[9];
    #pragma unroll
    for (int k = 0; k < 9; ++k) { f[k] = scat[k]; wkk[k] = scat[9 + k]; }

    // ---- Phase 3: two-stage 3x3 stencil, strip per thread ----
    const int r  = t >> 2;                // row 0..63
    const int xo = (t & 3) << 4;          // 0,16,32,48

    float yt[16], vc[16];
    #pragma unroll
    for (int i = 0; i < 16; ++i) yt[i] = 0.f;

    #pragma unroll
    for (int dy = 0; dy < 3; ++dy) {
        const float4* rp = (const float4*)&vpad[(r + dy) * VST + xo];
        float rw[20];
        *(float4*)&rw[0]  = rp[0]; *(float4*)&rw[4]  = rp[1];
        *(float4*)&rw[8]  = rp[2]; *(float4*)&rw[12] = rp[3];
        *(float4*)&rw[16] = rp[4];
        #pragma unroll
        for (int i = 0; i < 16; ++i) {
            yt[i] = fmaf(f[dy * 3 + 0], rw[2 + i], yt[i]);
            yt[i] = fmaf(f[dy * 3 + 1], rw[3 + i], yt[i]);
            yt[i] = fmaf(f[dy * 3 + 2], rw[4 + i], yt[i]);
        }
        if (dy == 1) {
            #pragma unroll
            for (int i = 0; i < 16; ++i) vc[i] = rw[3 + i];
        }
    }
    float pc[16];
    #pragma unroll
    for (int i = 0; i < 16; ++i) {
        float d = vc[i] - yt[i];
        pc[i] = __expf(-d * d) * vc[i];
        ppad[(r + 1) * VST + 3 + xo + i] = pc[i];
    }
    __syncthreads();

    #pragma unroll
    for (int dy = 0; dy < 3; ++dy) {
        const float4* rp = (const float4*)&vpad[(r + dy) * VST + xo];
        const float4* pp = (const float4*)&ppad[(r + dy) * VST + xo];
        float vr[20], prw[20];
        *(float4*)&vr[0]   = rp[0]; *(float4*)&vr[4]   = rp[1];
        *(float4*)&vr[8]   = rp[2]; *(float4*)&vr[12]  = rp[3];
        *(float4*)&vr[16]  = rp[4];
        *(float4*)&prw[0]  = pp[0]; *(float4*)&prw[4]  = pp[1];
        *(float4*)&prw[8]  = pp[2]; *(float4*)&prw[12] = pp[3];
        *(float4*)&prw[16] = pp[4];
        #pragma unroll
        for (int i = 0; i < 16; ++i) {
            float prodc = pc[i];
            #pragma unroll
            for (int kx = 0; kx < 3; ++kx) {
                float vn = vr[2 + i + kx];
                float pn = prw[2 + i + kx];
                float dw = fabsf(pn - prodc);
                float sg = sigmoidf_(dw);
                yt[i] = fmaf(-sg * vn, wkk[dy * 3 + kx], yt[i]);
            }
        }
    }
    size_t base = (size_t)bc * 4096 + r * 64 + xo;
    #pragma unroll
    for (int i = 0; i < 4; ++i) {
        float4 o = make_float4(yt[4*i], yt[4*i+1], yt[4*i+2], yt[4*i+3]);
        *(float4*)&y_out[base + 4 * i] = o;
    }

    // ---- Phase 4: q projection for own bc (threads 0..99) ----
    if (t < 100) {
        float s = bd[t];
        const float* wr = Wd + t * 18;
        #pragma unroll
        for (int k = 0; k < 18; ++k) s = fmaf(scat[k], wr[k], s);
        q_out[(size_t)t * 1024 + bc] = s;
    }
}

extern "C" void kernel_launch(void* const* d_in, const int* in_sizes, int n_in,
                              void* d_out, int out_size, void* d_ws, size_t ws_size,
                              hipStream_t stream) {
    const float* query = (const float*)d_in[0];
    const float* value = (const float*)d_in[1];
    // d_in[2] hard_sigmoid_masks: unused by the reference
    const float* W1    = (const float*)d_in[3];
    const float* b1    = (const float*)d_in[4];
    const float* gamma = (const float*)d_in[5];
    const float* beta  = (const float*)d_in[6];
    const float* mean  = (const float*)d_in[7];
    const float* var   = (const float*)d_in[8];
    const float* W2    = (const float*)d_in[9];
    const float* b2    = (const float*)d_in[10];
    const float* Wl    = (const float*)d_in[11];
    const float* bl    = (const float*)d_in[12];
    const float* Wd    = (const float*)d_in[13];
    const float* bd    = (const float*)d_in[14];

    float* ws = (float*)d_ws;
    int*   cnt    = (int*)d_ws;    // 544 ints (2 phases x 272)
    float* pooled = ws + 1024;     // 1024
    float* dp     = ws + 2048;     // 4096

    float* q_out = (float*)d_out;            // 102400 floats
    float* y_out = (float*)d_out + 102400;   // 4194304 floats

    // zero barrier counters every call (captured into the graph)
    hipMemsetAsync(cnt, 0, 544 * sizeof(int), stream);

    hipLaunchKernelGGL(fused_kernel, dim3(1024), dim3(256), 0, stream,
                       value, query, W1, b1, gamma, beta, mean, var,
                       W2, b2, Wl, bl, Wd, bd,
                       cnt, pooled, dp, q_out, y_out);
}

// Round 8
// 33.822 us; speedup vs baseline: 4.2339x; 4.2339x over previous
//
#include <hip/hip_runtime.h>
#include <cstddef>

#define BN_EPS 1e-5f
#define VST 68   // LDS row stride (floats): 272B = 17*16B -> 16B-aligned rows

__device__ __forceinline__ float sigmoidf_(float x) {
    return __builtin_amdgcn_rcpf(1.0f + __expf(-x));
}

// Division/exp-free sigmoid for x >= 0: clamped cubic, P(0)=0.5 exact,
// fit at {1.25, 3.75, 5}; max err ~0.0075 on [0,5], <=0.0067 beyond (clamp).
__device__ __forceinline__ float sig_poly_(float x) {
    float t = fminf(x, 5.0f);
    return fmaf(t, fmaf(t, fmaf(t, 0.003997859f, -0.05783463f), 0.28788663f), 0.5f);
}

// K1: pool (blocks 0..1023) + lin = query.Wl + bl (blocks 1024..1095)
__global__ __launch_bounds__(256) void pool_lin_kernel(
    const float* __restrict__ value, const float* __restrict__ query,
    const float* __restrict__ Wl, const float* __restrict__ bl,
    float* __restrict__ pooled, float* __restrict__ linbuf) {
    int t = threadIdx.x;
    if (blockIdx.x >= 1024) {
        __shared__ float sWl[1800];
        for (int i = t; i < 1800; i += 256) sWl[i] = Wl[i];
        __syncthreads();
        int g = (blockIdx.x - 1024) * 256 + t;     // 0..18431
        int k = g >> 10, bc = g & 1023;
        float s = bl[k];
        const float* wlr = &sWl[k * 100];
        #pragma unroll 4
        for (int q = 0; q < 100; ++q) s = fmaf(query[q * 1024 + bc], wlr[q], s);
        linbuf[bc * 18 + k] = s;
        return;
    }
    int bc = blockIdx.x;
    const float4* vp = (const float4*)(value + (size_t)bc * 4096);
    float s = 0.f;
    #pragma unroll
    for (int i = 0; i < 4; ++i) {
        float4 v = vp[t + 256 * i];
        s += v.x + v.y + v.z + v.w;
    }
    #pragma unroll
    for (int off = 32; off > 0; off >>= 1) s += __shfl_down(s, off);
    __shared__ float ws4[4];
    if ((t & 63) == 0) ws4[t >> 6] = s;
    __syncthreads();
    if (t == 0) pooled[bc] = (ws4[0] + ws4[1] + ws4[2] + ws4[3]) * (1.0f / 4096.0f);
}

// K2: dp = relu(BN(pooled @ W1^T + b1)) -> (4,1024).  One wave per output.
__global__ __launch_bounds__(256) void fc1_kernel(
    const float* __restrict__ pooled, const float* __restrict__ W1,
    const float* __restrict__ b1, const float* __restrict__ gamma,
    const float* __restrict__ beta, const float* __restrict__ mean,
    const float* __restrict__ var, float* __restrict__ dp) {
    int wid  = blockIdx.x * 4 + (threadIdx.x >> 6);   // 0..4095
    int lane = threadIdx.x & 63;
    int b = wid >> 10, j = wid & 1023;
    const float4* pr = (const float4*)(pooled + b * 256);
    const float4* wr = (const float4*)(W1 + (size_t)j * 256);
    float4 p = pr[lane], w = wr[lane];
    float s = p.x * w.x + p.y * w.y + p.z * w.z + p.w * w.w;
    #pragma unroll
    for (int off = 32; off > 0; off >>= 1) s += __shfl_down(s, off);
    if (lane == 0) {
        s += b1[j];
        s = (s - mean[j]) * rsqrtf(var[j] + BN_EPS) * gamma[j] + beta[j];
        dp[wid] = fmaxf(s, 0.f);
    }
}

// K3: fused fc2-gates + two-stage 3x3 stencil + q projection.
// One block per (b,c) plane (1024 blocks, 256 threads).
// vpad[row][col]: plane value[y][x] at row=y+1, col=x+3; halo cells zero.
// Neighbor k=(ky,kx) of pixel (y,x) lives at row y+ky, col 2+x+kx.
__global__ __launch_bounds__(256, 4) void stencil_kernel(
    const float* __restrict__ value, const float* __restrict__ dp,
    const float* __restrict__ W2, const float* __restrict__ b2,
    const float* __restrict__ linbuf, const float* __restrict__ Wd,
    const float* __restrict__ bd,
    float* __restrict__ q_out, float* __restrict__ y_out) {

    __shared__ __align__(16) float vpad[66 * VST];
    __shared__ __align__(16) float ppad[66 * VST];
    __shared__ float scat[18];
    __shared__ float gAB[2];

    const int t  = threadIdx.x;
    const int bc = blockIdx.x;            // 0..1023
    const int b  = bc >> 8, c = bc & 255;
    const int w  = t >> 6, lane = t & 63;

    // fc2 gate dots (waves 0,1) -- issue global loads early
    float sgate = 0.f;
    if (w < 2) {
        const float4* dpr  = (const float4*)(dp + b * 1024);
        const float4* wrow = (const float4*)(W2 + (size_t)(c + w * 256) * 1024);
        #pragma unroll
        for (int j = 0; j < 4; ++j) {
            float4 d = dpr[lane + 64 * j], ww = wrow[lane + 64 * j];
            sgate += d.x * ww.x + d.y * ww.y + d.z * ww.z + d.w * ww.w;
        }
    }

    // halo zero: 260 cells (rows 0,65 cols 2..67; cols 2,67 rows 1..64)
    for (int i = t; i < 260; i += 256) {
        int row, col;
        if (i < 132) { row = (i & 1) ? 65 : 0; col = 2 + (i >> 1); }
        else { int u = i - 132; row = 1 + (u & 63); col = (u & 64) ? 67 : 2; }
        vpad[row * VST + col] = 0.f;
        ppad[row * VST + col] = 0.f;
    }
    // load value plane (coalesced -> conflict-free LDS writes)
    const float* vp = value + (size_t)bc * 4096;
    #pragma unroll
    for (int i = 0; i < 16; ++i) {
        int idx = (i << 8) + t;
        vpad[((idx >> 6) + 1) * VST + 3 + (idx & 63)] = vp[idx];
    }

    // finish gates
    if (w < 2) {
        #pragma unroll
        for (int off = 32; off > 0; off >>= 1) sgate += __shfl_xor(sgate, off);
        if (lane == 0) gAB[w] = sigmoidf_(sgate + b2[c + w * 256]);
    }
    float lv = (t < 18) ? linbuf[bc * 18 + t] : 0.f;
    __syncthreads();
    if (t < 18) scat[t] = lv * (t < 9 ? gAB[0] : gAB[1]);
    __syncthreads();

    float f[9], wkk[9];
    #pragma unroll
    for (int k = 0; k < 9; ++k) { f[k] = scat[k]; wkk[k] = scat[9 + k]; }

    // ---- stage 1: y_temp = 3x3 conv(value, f), strip per thread ----
    const int r  = t >> 2;                // row 0..63
    const int xo = (t & 3) << 4;          // 0,16,32,48

    float yt[16], vc[16];
    #pragma unroll
    for (int i = 0; i < 16; ++i) yt[i] = 0.f;

    #pragma unroll
    for (int dy = 0; dy < 3; ++dy) {
        const float4* rp = (const float4*)&vpad[(r + dy) * VST + xo];
        float rw[20];
        *(float4*)&rw[0]  = rp[0]; *(float4*)&rw[4]  = rp[1];
        *(float4*)&rw[8]  = rp[2]; *(float4*)&rw[12] = rp[3];
        *(float4*)&rw[16] = rp[4];
        #pragma unroll
        for (int i = 0; i < 16; ++i) {
            yt[i] = fmaf(f[dy * 3 + 0], rw[2 + i], yt[i]);
            yt[i] = fmaf(f[dy * 3 + 1], rw[3 + i], yt[i]);
            yt[i] = fmaf(f[dy * 3 + 2], rw[4 + i], yt[i]);
        }
        if (dy == 1) {
            #pragma unroll
            for (int i = 0; i < 16; ++i) vc[i] = rw[3 + i];
        }
    }
    float pc[16];
    #pragma unroll
    for (int i = 0; i < 16; ++i) {
        float d = vc[i] - yt[i];
        pc[i] = __expf(-d * d) * vc[i];
        ppad[(r + 1) * VST + 3 + xo + i] = pc[i];
    }
    __syncthreads();

    // ---- stage 2: y = y_temp - sum_k sig(|prod_k - prod_c|) * value_k * wk_k
    #pragma unroll
    for (int dy = 0; dy < 3; ++dy) {
        const float4* rp = (const float4*)&vpad[(r + dy) * VST + xo];
        const float4* pp = (const float4*)&ppad[(r + dy) * VST + xo];
        float vr[20], prw[20];
        *(float4*)&vr[0]   = rp[0]; *(float4*)&vr[4]   = rp[1];
        *(float4*)&vr[8]   = rp[2]; *(float4*)&vr[12]  = rp[3];
        *(float4*)&vr[16]  = rp[4];
        *(float4*)&prw[0]  = pp[0]; *(float4*)&prw[4]  = pp[1];
        *(float4*)&prw[8]  = pp[2]; *(float4*)&prw[12] = pp[3];
        *(float4*)&prw[16] = pp[4];
        #pragma unroll
        for (int i = 0; i < 16; ++i) {
            float prodc = pc[i];
            #pragma unroll
            for (int kx = 0; kx < 3; ++kx) {
                float vn = vr[2 + i + kx];
                float pn = prw[2 + i + kx];
                float dw = fabsf(pn - prodc);
                float sg = sig_poly_(dw);          // trans-free sigmoid
                yt[i] = fmaf(-sg * vn, wkk[dy * 3 + kx], yt[i]);
            }
        }
    }
    size_t base = (size_t)bc * 4096 + r * 64 + xo;
    #pragma unroll
    for (int i = 0; i < 4; ++i) {
        float4 o = make_float4(yt[4*i], yt[4*i+1], yt[4*i+2], yt[4*i+3]);
        *(float4*)&y_out[base + 4 * i] = o;
    }

    // ---- q projection for own bc (threads 0..99) ----
    if (t < 100) {
        float s = bd[t];
        const float* wr = Wd + t * 18;
        #pragma unroll
        for (int k = 0; k < 18; ++k) s = fmaf(scat[k], wr[k], s);
        q_out[(size_t)t * 1024 + bc] = s;
    }
}

extern "C" void kernel_launch(void* const* d_in, const int* in_sizes, int n_in,
                              void* d_out, int out_size, void* d_ws, size_t ws_size,
                              hipStream_t stream) {
    const float* query = (const float*)d_in[0];
    const float* value = (const float*)d_in[1];
    // d_in[2] hard_sigmoid_masks: unused by the reference
    const float* W1    = (const float*)d_in[3];
    const float* b1    = (const float*)d_in[4];
    const float* gamma = (const float*)d_in[5];
    const float* beta  = (const float*)d_in[6];
    const float* mean  = (const float*)d_in[7];
    const float* var   = (const float*)d_in[8];
    const float* W2    = (const float*)d_in[9];
    const float* b2    = (const float*)d_in[10];
    const float* Wl    = (const float*)d_in[11];
    const float* bl    = (const float*)d_in[12];
    const float* Wd    = (const float*)d_in[13];
    const float* bd    = (const float*)d_in[14];

    float* ws = (float*)d_ws;
    float* pooled = ws;            // 1024
    float* dp     = ws + 1024;     // 4096
    float* linbuf = ws + 5120;     // 18432

    float* q_out = (float*)d_out;            // 102400 floats
    float* y_out = (float*)d_out + 102400;   // 4194304 floats

    hipLaunchKernelGGL(pool_lin_kernel, dim3(1096), dim3(256), 0, stream,
                       value, query, Wl, bl, pooled, linbuf);
    hipLaunchKernelGGL(fc1_kernel,      dim3(1024), dim3(256), 0, stream,
                       pooled, W1, b1, gamma, beta, mean, var, dp);
    hipLaunchKernelGGL(stencil_kernel,  dim3(1024), dim3(256), 0, stream,
                       value, dp, W2, b2, linbuf, Wd, bd, q_out, y_out);
}

// Round 9
// 33.433 us; speedup vs baseline: 4.2831x; 1.0116x over previous
//
#include <hip/hip_runtime.h>
#include <cstddef>

#define BN_EPS 1e-5f

__device__ __forceinline__ float sigmoidf_(float x) {
    return __builtin_amdgcn_rcpf(1.0f + __expf(-x));
}

// Division/exp-free sigmoid for x >= 0: clamped cubic, P(0)=0.5 exact,
// max err ~0.0075 on [0,5], <=0.0067 beyond (clamp).  Validated in R8.
__device__ __forceinline__ float sig_poly_(float x) {
    float t = fminf(x, 5.0f);
    return fmaf(t, fmaf(t, fmaf(t, 0.003997859f, -0.05783463f), 0.28788663f), 0.5f);
}

// K1: pool (blocks 0..1023) + lin = query.Wl + bl (blocks 1024..1095)
__global__ __launch_bounds__(256) void pool_lin_kernel(
    const float* __restrict__ value, const float* __restrict__ query,
    const float* __restrict__ Wl, const float* __restrict__ bl,
    float* __restrict__ pooled, float* __restrict__ linbuf) {
    int t = threadIdx.x;
    if (blockIdx.x >= 1024) {
        __shared__ float sWl[1800];
        for (int i = t; i < 1800; i += 256) sWl[i] = Wl[i];
        __syncthreads();
        int g = (blockIdx.x - 1024) * 256 + t;     // 0..18431
        int k = g >> 10, bc = g & 1023;
        float s = bl[k];
        const float* wlr = &sWl[k * 100];
        #pragma unroll 4
        for (int q = 0; q < 100; ++q) s = fmaf(query[q * 1024 + bc], wlr[q], s);
        linbuf[bc * 18 + k] = s;
        return;
    }
    int bc = blockIdx.x;
    const float4* vp = (const float4*)(value + (size_t)bc * 4096);
    float s = 0.f;
    #pragma unroll
    for (int i = 0; i < 4; ++i) {
        float4 v = vp[t + 256 * i];
        s += v.x + v.y + v.z + v.w;
    }
    #pragma unroll
    for (int off = 32; off > 0; off >>= 1) s += __shfl_down(s, off);
    __shared__ float ws4[4];
    if ((t & 63) == 0) ws4[t >> 6] = s;
    __syncthreads();
    if (t == 0) pooled[bc] = (ws4[0] + ws4[1] + ws4[2] + ws4[3]) * (1.0f / 4096.0f);
}

// K2: dp = relu(BN(pooled @ W1^T + b1)) -> (4,1024).  One wave per output.
__global__ __launch_bounds__(256) void fc1_kernel(
    const float* __restrict__ pooled, const float* __restrict__ W1,
    const float* __restrict__ b1, const float* __restrict__ gamma,
    const float* __restrict__ beta, const float* __restrict__ mean,
    const float* __restrict__ var, float* __restrict__ dp) {
    int wid  = blockIdx.x * 4 + (threadIdx.x >> 6);   // 0..4095
    int lane = threadIdx.x & 63;
    int b = wid >> 10, j = wid & 1023;
    const float4* pr = (const float4*)(pooled + b * 256);
    const float4* wr = (const float4*)(W1 + (size_t)j * 256);
    float4 p = pr[lane], w = wr[lane];
    float s = p.x * w.x + p.y * w.y + p.z * w.z + p.w * w.w;
    #pragma unroll
    for (int off = 32; off > 0; off >>= 1) s += __shfl_down(s, off);
    if (lane == 0) {
        s += b1[j];
        s = (s - mean[j]) * rsqrtf(var[j] + BN_EPS) * gamma[j] + beta[j];
        dp[wid] = fmaxf(s, 0.f);
    }
}

// K3: fused fc2-gates + register-streaming two-stage 3x3 stencil + q proj.
// One block per (b,c) plane.  Lane x owns column x; wave w owns rows 16w..16w+15.
// Rolling 4-row window in registers; L/R neighbors via wave shuffles; no LDS
// for plane data -> zero bank conflicts, no __syncthreads in the row loop.
__global__ __launch_bounds__(256) void stencil_kernel(
    const float* __restrict__ value, const float* __restrict__ dp,
    const float* __restrict__ W2, const float* __restrict__ b2,
    const float* __restrict__ linbuf, const float* __restrict__ Wd,
    const float* __restrict__ bd,
    float* __restrict__ q_out, float* __restrict__ y_out) {

    __shared__ float scat[18];
    __shared__ float gAB[2];

    const int t  = threadIdx.x;
    const int bc = blockIdx.x;            // 0..1023
    const int b  = bc >> 8, c = bc & 255;
    const int w  = t >> 6, lane = t & 63;

    // fc2 gate dots (waves 0,1)
    if (w < 2) {
        const float4* dpr  = (const float4*)(dp + b * 1024);
        const float4* wrow = (const float4*)(W2 + (size_t)(c + w * 256) * 1024);
        float sg = 0.f;
        #pragma unroll
        for (int j = 0; j < 4; ++j) {
            float4 d = dpr[lane + 64 * j], ww = wrow[lane + 64 * j];
            sg += d.x * ww.x + d.y * ww.y + d.z * ww.z + d.w * ww.w;
        }
        #pragma unroll
        for (int off = 32; off > 0; off >>= 1) sg += __shfl_xor(sg, off);
        if (lane == 0) gAB[w] = sigmoidf_(sg + b2[c + w * 256]);
    }
    float lv = (t < 18) ? linbuf[bc * 18 + t] : 0.f;
    __syncthreads();
    if (t < 18) scat[t] = lv * (t < 9 ? gAB[0] : gAB[1]);
    __syncthreads();

    float f[9], wk[9];
    #pragma unroll
    for (int k = 0; k < 9; ++k) { f[k] = scat[k]; wk[k] = scat[9 + k]; }

    const int y0 = w << 4;                // wave's band start row
    const float* vp = value + (size_t)bc * 4096 + lane;
    float*       yp = y_out + (size_t)bc * 4096 + lane;

    // rolling window registers: rows A=y-2, B=y-1, C=y, D=y+1 (L,C,R each)
    float vA_l = 0.f, vA_c = 0.f, vA_r = 0.f;
    float vB_c = ((unsigned)(y0 - 2) < 64u) ? vp[(y0 - 2) * 64] : 0.f;
    float vC_c = ((unsigned)(y0 - 1) < 64u) ? vp[(y0 - 1) * 64] : 0.f;
    float vB_l = __shfl_up(vB_c, 1);   if (lane == 0)  vB_l = 0.f;
    float vB_r = __shfl_down(vB_c, 1); if (lane == 63) vB_r = 0.f;
    float vC_l = __shfl_up(vC_c, 1);   if (lane == 0)  vC_l = 0.f;
    float vC_r = __shfl_down(vC_c, 1); if (lane == 63) vC_r = 0.f;
    float p2_l = 0.f, p2_c = 0.f, p2_r = 0.f;
    float p1_l = 0.f, p1_c = 0.f, p1_r = 0.f;
    float ytP  = 0.f;

    #pragma unroll
    for (int k = 0; k < 18; ++k) {
        const int y = y0 - 1 + k;         // conv row this iteration
        // load row y+1
        float vD_c = ((unsigned)(y + 1) < 64u) ? vp[(y + 1) * 64] : 0.f;
        float vD_l = __shfl_up(vD_c, 1);   if (lane == 0)  vD_l = 0.f;
        float vD_r = __shfl_down(vD_c, 1); if (lane == 63) vD_r = 0.f;

        // stage 1: y_temp at row y (rows y-1,y,y+1 = B,C,D)
        float ytN;
        ytN = f[0] * vB_l;
        ytN = fmaf(f[1], vB_c, ytN);
        ytN = fmaf(f[2], vB_r, ytN);
        ytN = fmaf(f[3], vC_l, ytN);
        ytN = fmaf(f[4], vC_c, ytN);
        ytN = fmaf(f[5], vC_r, ytN);
        ytN = fmaf(f[6], vD_l, ytN);
        ytN = fmaf(f[7], vD_c, ytN);
        ytN = fmaf(f[8], vD_r, ytN);
        float d    = vC_c - ytN;
        float p0_c = __expf(-d * d) * vC_c;          // prod at row y
        float p0_l = __shfl_up(p0_c, 1);   if (lane == 0)  p0_l = 0.f;
        float p0_r = __shfl_down(p0_c, 1); if (lane == 63) p0_r = 0.f;

        // stage 2: output row z = y-1 (valid for k >= 2)
        if (k >= 2) {
            const float pcc = p1_c;                  // prod at (z, x)
            float acc = ytP;
            acc = fmaf(-sig_poly_(fabsf(p2_l - pcc)) * vA_l, wk[0], acc);
            acc = fmaf(-sig_poly_(fabsf(p2_c - pcc)) * vA_c, wk[1], acc);
            acc = fmaf(-sig_poly_(fabsf(p2_r - pcc)) * vA_r, wk[2], acc);
            acc = fmaf(-sig_poly_(fabsf(p1_l - pcc)) * vB_l, wk[3], acc);
            acc = fmaf(-sig_poly_(fabsf(p1_c - pcc)) * vB_c, wk[4], acc);
            acc = fmaf(-sig_poly_(fabsf(p1_r - pcc)) * vB_r, wk[5], acc);
            acc = fmaf(-sig_poly_(fabsf(p0_l - pcc)) * vC_l, wk[6], acc);
            acc = fmaf(-sig_poly_(fabsf(p0_c - pcc)) * vC_c, wk[7], acc);
            acc = fmaf(-sig_poly_(fabsf(p0_r - pcc)) * vC_r, wk[8], acc);
            yp[(y - 1) * 64] = acc;
        }
        // rotate window
        vA_l = vB_l; vA_c = vB_c; vA_r = vB_r;
        vB_l = vC_l; vB_c = vC_c; vB_r = vC_r;
        vC_l = vD_l; vC_c = vD_c; vC_r = vD_r;
        p2_l = p1_l; p2_c = p1_c; p2_r = p1_r;
        p1_l = p0_l; p1_c = p0_c; p1_r = p0_r;
        ytP  = ytN;
    }

    // q projection for own bc (threads 0..99)
    if (t < 100) {
        float s = bd[t];
        const float* wr = Wd + t * 18;
        #pragma unroll
        for (int k = 0; k < 18; ++k) s = fmaf(scat[k], wr[k], s);
        q_out[(size_t)t * 1024 + bc] = s;
    }
}

extern "C" void kernel_launch(void* const* d_in, const int* in_sizes, int n_in,
                              void* d_out, int out_size, void* d_ws, size_t ws_size,
                              hipStream_t stream) {
    const float* query = (const float*)d_in[0];
    const float* value = (const float*)d_in[1];
    // d_in[2] hard_sigmoid_masks: unused by the reference
    const float* W1    = (const float*)d_in[3];
    const float* b1    = (const float*)d_in[4];
    const float* gamma = (const float*)d_in[5];
    const float* beta  = (const float*)d_in[6];
    const float* mean  = (const float*)d_in[7];
    const float* var   = (const float*)d_in[8];
    const float* W2    = (const float*)d_in[9];
    const float* b2    = (const float*)d_in[10];
    const float* Wl    = (const float*)d_in[11];
    const float* bl    = (const float*)d_in[12];
    const float* Wd    = (const float*)d_in[13];
    const float* bd    = (const float*)d_in[14];

    float* ws = (float*)d_ws;
    float* pooled = ws;            // 1024
    float* dp     = ws + 1024;     // 4096
    float* linbuf = ws + 5120;     // 18432

    float* q_out = (float*)d_out;            // 102400 floats
    float* y_out = (float*)d_out + 102400;   // 4194304 floats

    hipLaunchKernelGGL(pool_lin_kernel, dim3(1096), dim3(256), 0, stream,
                       value, query, Wl, bl, pooled, linbuf);
    hipLaunchKernelGGL(fc1_kernel,      dim3(1024), dim3(256), 0, stream,
                       pooled, W1, b1, gamma, beta, mean, var, dp);
    hipLaunchKernelGGL(stencil_kernel,  dim3(1024), dim3(256), 0, stream,
                       value, dp, W2, b2, linbuf, Wd, bd, q_out, y_out);
}